// Round 14
// baseline (386.839 us; speedup 1.0000x reference)
//
#include <hip/hip_runtime.h>
#include <hip/hip_bf16.h>
#include <math.h>

#define B_ 16
#define C_ 512
#define N_ 4096
#define NCOL (B_ * N_)  // 65536 columns (b, hw)

typedef short bf16x8 __attribute__((ext_vector_type(8)));
typedef ushort ushort8_t __attribute__((ext_vector_type(8)));
typedef float f32x4 __attribute__((ext_vector_type(4)));

__device__ __forceinline__ ushort f2bf(float f) {
    unsigned u = __float_as_uint(f);
    unsigned r = (u + 0x7FFFu + ((u >> 16) & 1u)) >> 16;
    return (ushort)r;
}
__device__ __forceinline__ float bf2f(ushort u) {
    return __uint_as_float((unsigned)u << 16);
}
__device__ __forceinline__ void gload_lds16(const void* g, void* l) {
    __builtin_amdgcn_global_load_lds(
        (const __attribute__((address_space(1))) unsigned int*)g,
        (__attribute__((address_space(3))) unsigned int*)l, 16, 0, 0);
}

// ---------------------------------------------------------------------------
// merged weight prep: Wqkvb[i] = bf16(Wqkv*g1), Woutb = bf16(Wout)
// ---------------------------------------------------------------------------
__global__ __launch_bounds__(256) void wprep2_k(const float* __restrict__ Wqkv,
                                                const float* __restrict__ g1,
                                                const float* __restrict__ Wout,
                                                ushort* __restrict__ Wqkvb,
                                                ushort* __restrict__ Woutb)
{
    int i = blockIdx.x * 256 + threadIdx.x;
    if (i < 196608) {                  // 1536*512/4 vectors
        float4 wv = reinterpret_cast<const float4*>(Wqkv)[i];
        const float4 gv = *reinterpret_cast<const float4*>(g1 + ((i * 4) & 511));
        ushort4 u;
        u.x = f2bf(wv.x * gv.x); u.y = f2bf(wv.y * gv.y);
        u.z = f2bf(wv.z * gv.z); u.w = f2bf(wv.w * gv.w);
        reinterpret_cast<ushort4*>(Wqkvb)[i] = u;
    } else {
        int j = i - 196608;            // < 65536
        float4 wv = reinterpret_cast<const float4*>(Wout)[j];
        ushort4 u;
        u.x = f2bf(wv.x); u.y = f2bf(wv.y); u.z = f2bf(wv.z); u.w = f2bf(wv.w);
        reinterpret_cast<ushort4*>(Woutb)[j] = u;
    }
}

// ---------------------------------------------------------------------------
// transpose v2: block = (64 n) x (all 512 c) x b.  float4 loads, LDS dbuf,
// Xt[b][n][c] = bf16(x[b][c][n]); rs1[b][n] computed in-kernel (full column).
// ---------------------------------------------------------------------------
__global__ __launch_bounds__(256) void transpose_k(const float* __restrict__ X,
                                                   ushort* __restrict__ Xt,
                                                   float* __restrict__ rs1)
{
    __shared__ float t[2][64][68];
    __shared__ float sr[16][64];
    const int b = blockIdx.y, n0 = blockIdx.x * 64;
    const int tid = threadIdx.x;
    const int tg = tid >> 4, tl = tid & 15;
    float sq[4] = {0.f, 0.f, 0.f, 0.f};
    for (int chunk = 0; chunk < 8; ++chunk) {
        const int buf = chunk & 1;
        const float* xp = X + ((size_t)b * C_ + chunk * 64) * N_ + n0;
        #pragma unroll
        for (int j = 0; j < 4; ++j) {
            int c = tg + j * 16;
            float4 v = *reinterpret_cast<const float4*>(xp + (size_t)c * N_ + tl * 4);
            *reinterpret_cast<float4*>(&t[buf][c][tl * 4]) = v;
            sq[0] += v.x * v.x; sq[1] += v.y * v.y;
            sq[2] += v.z * v.z; sq[3] += v.w * v.w;
        }
        __syncthreads();
        #pragma unroll
        for (int i = 0; i < 4; ++i) {
            int nl = tg + i * 16, cl = tl * 4;
            ushort4 u;
            u.x = f2bf(t[buf][cl + 0][nl]);
            u.y = f2bf(t[buf][cl + 1][nl]);
            u.z = f2bf(t[buf][cl + 2][nl]);
            u.w = f2bf(t[buf][cl + 3][nl]);
            *reinterpret_cast<ushort4*>(
                Xt + ((size_t)b * N_ + n0 + nl) * 512 + chunk * 64 + cl) = u;
        }
    }
    #pragma unroll
    for (int j = 0; j < 4; ++j) sr[tg][tl * 4 + j] = sq[j];
    __syncthreads();
    if (tid < 64) {
        float s = 0.f;
        #pragma unroll
        for (int g = 0; g < 16; ++g) s += sr[g][tid];
        rs1[(size_t)b * N_ + n0 + tid] = 22.627416998f / fmaxf(sqrtf(s), 1e-12f);
    }
}

// ---------------------------------------------------------------------------
// MFMA GEMM1 (256x256 tile, 8 waves 2x4, BK=64, double-buffered LDS,
// per-phase interleave + counted vmcnt):  acc[o][n] = sum_c A[o][c]*Bt[b][n][c]
// Epilogue: acc *= rs1[b][n];
//   part 0 (q): softmax over d * 0.125 -> qT2[b][n][h*64+d] bf16 (8B stores)
//   part 1 (k): bf16 raw + per-64-col partial (max, sumexp) -> kpm/kps (LSE)
//   part 2 (v): bf16 raw
// (k/v scalar stores FROZEN: R10 split / R12 runtime-swap both regressed)
// ---------------------------------------------------------------------------
__global__ __launch_bounds__(512, 2)
void mfma_gemm(const ushort* __restrict__ A, const ushort* __restrict__ Bt,
               const float* __restrict__ rs1,
               ushort* __restrict__ qT2, ushort* __restrict__ kd,
               ushort* __restrict__ vd,
               float* __restrict__ kpm, float* __restrict__ kps)
{
    // lds[buf][A/B][256 rows][8 chunks][16B]
    __shared__ __align__(16) char lds[2][2][32768];
    const int b  = blockIdx.z;
    const int n0 = blockIdx.x * 256;
    const int m0 = blockIdx.y * 256;
    const int tid = threadIdx.x;
    const int w = tid >> 6, l = tid & 63;
    const int wm = w >> 2, wn = w & 3;          // 2 x 4 waves
    const int lq = l >> 4, lr = l & 15;
    const ushort* Bb = Bt + (size_t)b * N_ * 512;

    f32x4 acc[8][4];
    #pragma unroll
    for (int i = 0; i < 8; ++i)
        #pragma unroll
        for (int j = 0; j < 4; ++j)
            #pragma unroll
            for (int r = 0; r < 4; ++r) acc[i][j][r] = 0.f;

#define STAGE_STEP(t, i)                                                      \
    do {                                                                      \
        const int kb_ = (t) * 128;                                            \
        const int idx_ = (i) * 512 + tid;                                     \
        const int r_ = idx_ >> 3;                                             \
        const int ch_ = (idx_ & 7) ^ (r_ & 7);                                \
        gload_lds16((const char*)A + (size_t)(m0 + r_) * 1024 + kb_ + ch_ * 16,\
                    &lds[(t) & 1][0][idx_ * 16]);                             \
        gload_lds16((const char*)Bb + (size_t)(n0 + r_) * 1024 + kb_ + ch_ * 16,\
                    &lds[(t) & 1][1][idx_ * 16]);                             \
    } while (0)

    #pragma unroll
    for (int i = 0; i < 4; ++i) STAGE_STEP(0, i);

    bf16x8 bfr[4];
    #pragma unroll 2
    for (int t = 0; t < 8; ++t) {
        const char* As = lds[t & 1][0];
        const char* Bs = lds[t & 1][1];
        #pragma unroll
        for (int ph = 0; ph < 4; ++ph) {
            const int kk = ph >> 1, mg = ph & 1;
            bf16x8 af[4];
            if (ph != 0) {
                #pragma unroll
                for (int m2 = 0; m2 < 4; ++m2) {
                    int ra = wm * 128 + (mg * 4 + m2) * 16 + lr;
                    int ch = (kk * 4 + lq) ^ (ra & 7);
                    af[m2] = *(const bf16x8*)(As + ra * 128 + ch * 16);
                }
                if (mg == 0) {
                    #pragma unroll
                    for (int nf = 0; nf < 4; ++nf) {
                        int rb = wn * 64 + nf * 16 + lr;
                        int ch = (kk * 4 + lq) ^ (rb & 7);
                        bfr[nf] = *(const bf16x8*)(Bs + rb * 128 + ch * 16);
                    }
                }
            }
            if (t < 7) STAGE_STEP(t + 1, ph);
            if (ph == 0) {
                if (t < 7) { asm volatile("s_waitcnt vmcnt(2)" ::: "memory"); }
                else       { asm volatile("s_waitcnt vmcnt(0)" ::: "memory"); }
            }
            __builtin_amdgcn_s_barrier();
            if (ph == 0) {
                #pragma unroll
                for (int m2 = 0; m2 < 4; ++m2) {
                    int ra = wm * 128 + m2 * 16 + lr;
                    int ch = lq ^ (ra & 7);
                    af[m2] = *(const bf16x8*)(As + ra * 128 + ch * 16);
                }
                #pragma unroll
                for (int nf = 0; nf < 4; ++nf) {
                    int rb = wn * 64 + nf * 16 + lr;
                    int ch = lq ^ (rb & 7);
                    bfr[nf] = *(const bf16x8*)(Bs + rb * 128 + ch * 16);
                }
            }
            asm volatile("s_waitcnt lgkmcnt(0)" ::: "memory");
            __builtin_amdgcn_sched_barrier(0);
            __builtin_amdgcn_s_setprio(1);
            #pragma unroll
            for (int m2 = 0; m2 < 4; ++m2)
                #pragma unroll
                for (int nf = 0; nf < 4; ++nf)
                    acc[mg * 4 + m2][nf] = __builtin_amdgcn_mfma_f32_16x16x32_bf16(
                        af[m2], bfr[nf], acc[mg * 4 + m2][nf], 0, 0, 0);
            __builtin_amdgcn_s_setprio(0);
            __builtin_amdgcn_s_barrier();
        }
    }
#undef STAGE_STEP

    const int part = m0 >> 9;                       // block-uniform (0/1/2)
    const int mloc = (m0 & 511) + wm * 128;         // 0/128/256/384 within part
    const int nbase = n0 + wn * 64;
    if (part == 0) {
        // q: *rs1, softmax over the 64 d-rows of each head, *0.125,
        // write qT2[b][n][h*64+d] bf16 with packed 8B stores.
        #pragma unroll
        for (int hg = 0; hg < 2; ++hg) {
            const int head = (mloc >> 6) + hg;
            #pragma unroll
            for (int nf = 0; nf < 4; ++nf) {
                const int n = nbase + nf * 16 + lr;
                const float sc = rs1[(size_t)b * N_ + n];
                float v[4][4];
                float mx = -1e30f;
                #pragma unroll
                for (int m2 = 0; m2 < 4; ++m2)
                    #pragma unroll
                    for (int r = 0; r < 4; ++r) {
                        v[m2][r] = acc[hg * 4 + m2][nf][r] * sc;
                        mx = fmaxf(mx, v[m2][r]);
                    }
                mx = fmaxf(mx, __shfl_xor(mx, 16));
                mx = fmaxf(mx, __shfl_xor(mx, 32));
                float s = 0.f;
                #pragma unroll
                for (int m2 = 0; m2 < 4; ++m2)
                    #pragma unroll
                    for (int r = 0; r < 4; ++r) {
                        v[m2][r] = __expf(v[m2][r] - mx);
                        s += v[m2][r];
                    }
                s += __shfl_xor(s, 16);
                s += __shfl_xor(s, 32);
                const float r8 = 0.125f / s;
                ushort* qp = qT2 + ((size_t)b * N_ + n) * 512 + head * 64;
                #pragma unroll
                for (int m2 = 0; m2 < 4; ++m2) {
                    ushort4 u;
                    u.x = f2bf(v[m2][0] * r8);
                    u.y = f2bf(v[m2][1] * r8);
                    u.z = f2bf(v[m2][2] * r8);
                    u.w = f2bf(v[m2][3] * r8);
                    *reinterpret_cast<ushort4*>(qp + m2 * 16 + lq * 4) = u;
                }
            }
        }
    } else {
        ushort* dst = (part == 1) ? kd : vd;
        float sc4[4];
        #pragma unroll
        for (int nf = 0; nf < 4; ++nf)
            sc4[nf] = rs1[(size_t)b * N_ + nbase + nf * 16 + lr];
        #pragma unroll
        for (int nf = 0; nf < 4; ++nf) {
            const int n = nbase + nf * 16 + lr;
            #pragma unroll
            for (int mf = 0; mf < 8; ++mf) {
                const int o = mloc + mf * 16 + lq * 4;
                #pragma unroll
                for (int r = 0; r < 4; ++r)
                    dst[((size_t)b * 512 + o + r) * N_ + n] =
                        f2bf(acc[mf][nf][r] * sc4[nf]);
            }
        }
        if (part == 1 && kpm) {
            // per-row LSE partials over this wave's 64 columns (nf x lr)
            const int p = blockIdx.x * 4 + wn;       // 0..63
            #pragma unroll
            for (int mf = 0; mf < 8; ++mf)
                #pragma unroll
                for (int r = 0; r < 4; ++r) {
                    float v0 = acc[mf][0][r] * sc4[0];
                    float v1 = acc[mf][1][r] * sc4[1];
                    float v2 = acc[mf][2][r] * sc4[2];
                    float v3 = acc[mf][3][r] * sc4[3];
                    float m = fmaxf(fmaxf(v0, v1), fmaxf(v2, v3));
                    m = fmaxf(m, __shfl_xor(m, 1));
                    m = fmaxf(m, __shfl_xor(m, 2));
                    m = fmaxf(m, __shfl_xor(m, 4));
                    m = fmaxf(m, __shfl_xor(m, 8));
                    float s = __expf(v0 - m) + __expf(v1 - m)
                            + __expf(v2 - m) + __expf(v3 - m);
                    s += __shfl_xor(s, 1);
                    s += __shfl_xor(s, 2);
                    s += __shfl_xor(s, 4);
                    s += __shfl_xor(s, 8);
                    if (lr == 0) {
                        const int dk = mloc + mf * 16 + lq * 4 + r;
                        kpm[((size_t)p * B_ + b) * 512 + dk] = m;
                        kps[((size_t)p * B_ + b) * 512 + dk] = s;
                    }
                }
        }
    }
}

// ---------------------------------------------------------------------------
// kstat_merge: LSE-merge 64 partials per k-row -> rowm, rowr = 1/sumexp
// ---------------------------------------------------------------------------
__global__ __launch_bounds__(256) void kstat_merge_k(const float* __restrict__ kpm,
                                                     const float* __restrict__ kps,
                                                     float* __restrict__ rowm,
                                                     float* __restrict__ rowr)
{
    int idx = blockIdx.x * 256 + threadIdx.x;   // 0..8191 = b*512+dk
    int b = idx >> 9, dk = idx & 511;
    float m = -1e30f;
    #pragma unroll 8
    for (int p = 0; p < 64; ++p)
        m = fmaxf(m, kpm[((size_t)p * B_ + b) * 512 + dk]);
    float s = 0.f;
    #pragma unroll 8
    for (int p = 0; p < 64; ++p)
        s += kps[((size_t)p * B_ + b) * 512 + dk] *
             __expf(kpm[((size_t)p * B_ + b) * 512 + dk] - m);
    rowm[idx] = m;
    rowr[idx] = 1.f / s;
}

// ---------------------------------------------------------------------------
// fallback row stats (used when ws too small for partial arrays)
// ---------------------------------------------------------------------------
__global__ __launch_bounds__(256) void rowstat_k(const ushort* __restrict__ kk,
                                                 float* __restrict__ rowm,
                                                 float* __restrict__ rowr)
{
    const int row = blockIdx.x * 4 + (threadIdx.x >> 6);
    const int lane = threadIdx.x & 63;
    const ushort* p = kk + (size_t)row * N_;
    float vals[64];
    #pragma unroll
    for (int j = 0; j < 8; ++j) {
        ushort8_t u = *reinterpret_cast<const ushort8_t*>(p + lane * 8 + j * 512);
        #pragma unroll
        for (int t = 0; t < 8; ++t) vals[j * 8 + t] = bf2f(u[t]);
    }
    float mx = -1e30f;
    #pragma unroll
    for (int i = 0; i < 64; ++i) mx = fmaxf(mx, vals[i]);
    #pragma unroll
    for (int o = 32; o >= 1; o >>= 1) mx = fmaxf(mx, __shfl_xor(mx, o));
    float s = 0.f;
    #pragma unroll
    for (int i = 0; i < 64; ++i) s += __expf(vals[i] - mx);
    #pragma unroll
    for (int o = 32; o >= 1; o >>= 1) s += __shfl_xor(s, o);
    if (lane == 0) { rowm[row] = mx; rowr[row] = 1.f / s; }
}

// ---------------------------------------------------------------------------
// ctx (MFMA): ctxp[bh][chunk][d][e] = rowr[d] *
//     sum_{n in chunk} exp(k[bh][d][n]-rowm[d]) * v[bh][e][n]
// ---------------------------------------------------------------------------
__global__ __launch_bounds__(256) void ctx_k(const ushort* __restrict__ kk,
                                             const ushort* __restrict__ vv,
                                             const float* __restrict__ rowm,
                                             const float* __restrict__ rowr,
                                             float* __restrict__ ctxp)
{
    const int bh = blockIdx.x, chunk = blockIdx.y;
    const ushort* kp = kk + (size_t)bh * 64 * N_;
    const ushort* vp = vv + (size_t)bh * 64 * N_;
    __shared__ __align__(16) ushort kx[64 * 128];   // 16 KiB
    __shared__ __align__(16) ushort vx[64 * 128];   // 16 KiB
    __shared__ float rm[64];
    const int tid = threadIdx.x;
    const int w = tid >> 6, l = tid & 63;
    const int lq = l >> 4, lr = l & 15;
    const int we = w >> 1, wd = w & 1;              // e-half, d-half of 64x64
    if (tid < 64) rm[tid] = rowm[(size_t)bh * 64 + tid];
    __syncthreads();

    f32x4 acc[2][2];
    #pragma unroll
    for (int i = 0; i < 2; ++i)
        #pragma unroll
        for (int j = 0; j < 2; ++j)
            #pragma unroll
            for (int r = 0; r < 4; ++r) acc[i][j][r] = 0.f;

    for (int s = 0; s < 8; ++s) {
        const int n0 = chunk * 1024 + s * 128;
        #pragma unroll
        for (int i = 0; i < 4; ++i) {
            int idx = i * 256 + tid;
            int row = idx >> 4;
            int ch  = (idx & 15) ^ (row & 15);
            gload_lds16((const char*)(vp + (size_t)row * N_ + n0 + ch * 8),
                        (char*)vx + idx * 16);
        }
        #pragma unroll
        for (int i = 0; i < 4; ++i) {
            int idx = i * 256 + tid;
            int row = idx >> 4;
            int ch  = idx & 15;
            ushort8_t u = *reinterpret_cast<const ushort8_t*>(
                kp + (size_t)row * N_ + n0 + ch * 8);
            float m_ = rm[row];
            ushort8_t o;
            #pragma unroll
            for (int t = 0; t < 8; ++t) o[t] = f2bf(__expf(bf2f(u[t]) - m_));
            *(ushort8_t*)((char*)kx + (row * 16 + (ch ^ (row & 15))) * 16) = o;
        }
        __syncthreads();
        #pragma unroll
        for (int k2 = 0; k2 < 4; ++k2) {
            bf16x8 af[2], bfr[2];
            #pragma unroll
            for (int i = 0; i < 2; ++i) {
                int re = we * 32 + i * 16 + lr;
                int cha = (k2 * 4 + lq) ^ (re & 15);
                af[i] = *(const bf16x8*)((const char*)vx + (re * 16 + cha) * 16);
                int rd = wd * 32 + i * 16 + lr;
                int chb = (k2 * 4 + lq) ^ (rd & 15);
                bfr[i] = *(const bf16x8*)((const char*)kx + (rd * 16 + chb) * 16);
            }
            #pragma unroll
            for (int i = 0; i < 2; ++i)
                #pragma unroll
                for (int j = 0; j < 2; ++j)
                    acc[i][j] = __builtin_amdgcn_mfma_f32_16x16x32_bf16(
                        af[i], bfr[j], acc[i][j], 0, 0, 0);
        }
        __syncthreads();
    }
    // write ctxp[bh][chunk][d][e] (e contiguous -> float4), scale by rowr[d]
    float* cbase = ctxp + ((size_t)bh * 4 + chunk) * 4096;
    #pragma unroll
    for (int j = 0; j < 2; ++j) {
        const int d = wd * 32 + j * 16 + lr;
        const float rr = rowr[(size_t)bh * 64 + d];
        #pragma unroll
        for (int i = 0; i < 2; ++i) {
            const int e0 = we * 32 + i * 16 + lq * 4;
            float4 wv;
            wv.x = acc[i][j][0] * rr;
            wv.y = acc[i][j][1] * rr;
            wv.z = acc[i][j][2] * rr;
            wv.w = acc[i][j][3] * rr;
            *reinterpret_cast<float4*>(cbase + (size_t)d * 64 + e0) = wv;
        }
    }
}

// ---------------------------------------------------------------------------
// wcbuild (MFMA): Wc[b][o][h*64+d] = bf16( sum_e Wout[o][h*64+e] *
//                                          (sum_chunk ctxp[bh][chunk][d][e]) )
// ---------------------------------------------------------------------------
__global__ __launch_bounds__(256) void wcbuild_k(const ushort* __restrict__ Wb,
                                                 const float* __restrict__ ctxp,
                                                 ushort* __restrict__ Wc)
{
    const int oh = blockIdx.x, h = blockIdx.y, b = blockIdx.z;
    const int bh = b * 8 + h;
    __shared__ __align__(16) ushort ws[256 * 64];   // 32 KiB, Wout slice
    __shared__ __align__(16) ushort cs[64 * 64];    // 8 KiB, ctx[d][e]
    const int tid = threadIdx.x;
    const int w = tid >> 6, l = tid & 63;
    const int lq = l >> 4, lr = l & 15;

    #pragma unroll
    for (int i = 0; i < 8; ++i) {
        int idx = i * 256 + tid;
        int row = idx >> 3;
        int ch = (idx & 7) ^ (row & 7);
        gload_lds16(Wb + (size_t)(oh * 256 + row) * 512 + h * 64 + ch * 8,
                    (char*)ws + idx * 16);
    }
    {
        const float* cp = ctxp + (size_t)bh * 4 * 4096;
        const int d = tid >> 2, eb = (tid & 3) * 16;
        float vs[16];
        #pragma unroll
        for (int t4 = 0; t4 < 4; ++t4) {
            float4 a0 = *(const float4*)(cp + d * 64 + eb + t4 * 4);
            float4 a1 = *(const float4*)(cp + 4096 + d * 64 + eb + t4 * 4);
            float4 a2 = *(const float4*)(cp + 8192 + d * 64 + eb + t4 * 4);
            float4 a3 = *(const float4*)(cp + 12288 + d * 64 + eb + t4 * 4);
            vs[t4 * 4 + 0] = a0.x + a1.x + a2.x + a3.x;
            vs[t4 * 4 + 1] = a0.y + a1.y + a2.y + a3.y;
            vs[t4 * 4 + 2] = a0.z + a1.z + a2.z + a3.z;
            vs[t4 * 4 + 3] = a0.w + a1.w + a2.w + a3.w;
        }
        ushort8_t o0, o1;
        #pragma unroll
        for (int t = 0; t < 8; ++t) { o0[t] = f2bf(vs[t]); o1[t] = f2bf(vs[8 + t]); }
        const int c0 = (eb >> 3) ^ (d & 7);
        const int c1 = ((eb >> 3) + 1) ^ (d & 7);
        *(ushort8_t*)((char*)cs + (d * 8 + c0) * 16) = o0;
        *(ushort8_t*)((char*)cs + (d * 8 + c1) * 16) = o1;
    }
    __syncthreads();

    f32x4 acc[4][4];
    #pragma unroll
    for (int i = 0; i < 4; ++i)
        #pragma unroll
        for (int j = 0; j < 4; ++j)
            #pragma unroll
            for (int r = 0; r < 4; ++r) acc[i][j][r] = 0.f;

    #pragma unroll
    for (int kk = 0; kk < 2; ++kk) {
        bf16x8 af[4], bfr[4];
        #pragma unroll
        for (int mf = 0; mf < 4; ++mf) {
            int ra = w * 64 + mf * 16 + lr;
            int ch = (kk * 4 + lq) ^ (ra & 7);
            af[mf] = *(const bf16x8*)((const char*)ws + (ra * 8 + ch) * 16);
        }
        #pragma unroll
        for (int nf = 0; nf < 4; ++nf) {
            int rd = nf * 16 + lr;
            int ch = (kk * 4 + lq) ^ (rd & 7);
            bfr[nf] = *(const bf16x8*)((const char*)cs + (rd * 8 + ch) * 16);
        }
        #pragma unroll
        for (int mf = 0; mf < 4; ++mf)
            #pragma unroll
            for (int nf = 0; nf < 4; ++nf)
                acc[mf][nf] = __builtin_amdgcn_mfma_f32_16x16x32_bf16(
                    af[mf], bfr[nf], acc[mf][nf], 0, 0, 0);
    }

    ushort* wp = Wc + (size_t)b * 262144 + h * 64;
    #pragma unroll
    for (int mf = 0; mf < 4; ++mf)
        #pragma unroll
        for (int r = 0; r < 4; ++r) {
            const int o = oh * 256 + w * 64 + mf * 16 + lq * 4 + r;
            #pragma unroll
            for (int nf = 0; nf < 4; ++nf)
                wp[(size_t)o * 512 + nf * 16 + lr] = f2bf(acc[mf][nf][r]);
        }
}

// ---------------------------------------------------------------------------
// GEMM2 fused: out[b][o][n] = rmsnorm(Wc[b]@qT2[b] + bias) * g2, full column
// per block. 512 threads = 8 waves; wave w owns rows [w*64,w*64+64), n-tile 128.
// ---------------------------------------------------------------------------
__global__ __launch_bounds__(512, 2)
void gemm2_k(const ushort* __restrict__ Wc,     // [b][512][512] bf16
             const ushort* __restrict__ Bt,     // qT2 [b][n][512] bf16
             const float* __restrict__ bias,
             const float* __restrict__ g2,
             float* __restrict__ outp)
{
    __shared__ __align__(16) ushort As[512 * 64];   // 64 KiB
    __shared__ __align__(16) ushort Bs[128 * 64];   // 16 KiB
    const int b  = blockIdx.y;
    const int n0 = blockIdx.x * 128;
    const int tid = threadIdx.x;
    const int w = tid >> 6, l = tid & 63;
    const int lq = l >> 4, lr = l & 15;
    const ushort* A  = Wc + (size_t)b * 262144;
    const ushort* Bb = Bt + (size_t)b * N_ * 512;

    f32x4 acc[4][8];
    #pragma unroll
    for (int i = 0; i < 4; ++i)
        #pragma unroll
        for (int j = 0; j < 8; ++j)
            #pragma unroll
            for (int r = 0; r < 4; ++r) acc[i][j][r] = 0.f;

    for (int k0 = 0; k0 < 512; k0 += 64) {
        #pragma unroll
        for (int i = 0; i < 8; ++i) {
            int base = i * 512 + w * 64;
            int idx = base + l;
            int r = idx >> 3, ch = (idx & 7) ^ (r & 7);
            gload_lds16((const char*)A + (size_t)r * 1024 + k0 * 2 + ch * 16,
                        (char*)As + (size_t)base * 16);
        }
        #pragma unroll
        for (int i = 0; i < 2; ++i) {
            int base = i * 512 + w * 64;
            int idx = base + l;
            int r = idx >> 3, ch = (idx & 7) ^ (r & 7);
            gload_lds16((const char*)Bb + (size_t)(n0 + r) * 1024 + k0 * 2 + ch * 16,
                        (char*)Bs + (size_t)base * 16);
        }
        __syncthreads();
        #pragma unroll
        for (int kk = 0; kk < 2; ++kk) {
            bf16x8 af[4], bfv[8];
            #pragma unroll
            for (int mf = 0; mf < 4; ++mf) {
                int ra = w * 64 + mf * 16 + lr;
                int ch = (kk * 4 + lq) ^ (ra & 7);
                af[mf] = *(const bf16x8*)((const char*)As + ra * 128 + ch * 16);
            }
            #pragma unroll
            for (int nf = 0; nf < 8; ++nf) {
                int rb = nf * 16 + lr;
                int ch = (kk * 4 + lq) ^ (rb & 7);
                bfv[nf] = *(const bf16x8*)((const char*)Bs + rb * 128 + ch * 16);
            }
            #pragma unroll
            for (int mf = 0; mf < 4; ++mf)
                #pragma unroll
                for (int nf = 0; nf < 8; ++nf)
                    acc[mf][nf] = __builtin_amdgcn_mfma_f32_16x16x32_bf16(
                        af[mf], bfv[nf], acc[mf][nf], 0, 0, 0);
        }
        __syncthreads();
    }

    float4 bv[4], g2v[4];
    #pragma unroll
    for (int mf = 0; mf < 4; ++mf) {
        bv[mf]  = *reinterpret_cast<const float4*>(bias + w * 64 + mf * 16 + lq * 4);
        g2v[mf] = *reinterpret_cast<const float4*>(g2   + w * 64 + mf * 16 + lq * 4);
    }
    float csq[8] = {};
    #pragma unroll
    for (int mf = 0; mf < 4; ++mf)
        #pragma unroll
        for (int nf = 0; nf < 8; ++nf)
            #pragma unroll
            for (int r = 0; r < 4; ++r) {
                float wv = acc[mf][nf][r] + ((const float*)&bv[mf])[r];
                acc[mf][nf][r] = wv;
                csq[nf] += wv * wv;
            }
    #pragma unroll
    for (int nf = 0; nf < 8; ++nf) {
        csq[nf] += __shfl_xor(csq[nf], 16);
        csq[nf] += __shfl_xor(csq[nf], 32);
    }
    float* red  = (float*)As;
    float* rs2s = red + 1024;
    if (lq == 0) {
        #pragma unroll
        for (int nf = 0; nf < 8; ++nf)
            red[w * 128 + nf * 16 + lr] = csq[nf];
    }
    __syncthreads();
    if (tid < 128) {
        float s = 0.f;
        #pragma unroll
        for (int j = 0; j < 8; ++j) s += red[j * 128 + tid];
        rs2s[tid] = 22.627416998f / fmaxf(sqrtf(s), 1e-12f);
    }
    __syncthreads();
    #pragma unroll
    for (int nf = 0; nf < 8; ++nf) {
        const float rsv = rs2s[nf * 16 + lr];
        const int n = n0 + nf * 16 + lr;
        #pragma unroll
        for (int mf = 0; mf < 4; ++mf) {
            const int o = w * 64 + mf * 16 + lq * 4;
            float* p = outp + ((size_t)b * 512 + o) * N_ + n;
            #pragma unroll
            for (int r = 0; r < 4; ++r)
                p[(size_t)r * N_] = acc[mf][nf][r] * rsv * ((const float*)&g2v[mf])[r];
        }
    }
}

// ---------------------------------------------------------------------------
extern "C" void kernel_launch(void* const* d_in, const int* in_sizes, int n_in,
                              void* d_out, int out_size, void* d_ws, size_t ws_size,
                              hipStream_t stream)
{
    const float* x    = (const float*)d_in[0];
    const float* g1   = (const float*)d_in[1];
    const float* Wqkv = (const float*)d_in[2];
    const float* Wout = (const float*)d_in[3];
    const float* bout = (const float*)d_in[4];
    const float* g2   = (const float*)d_in[5];
    float* out = (float*)d_out;

    // ws layout:
    //   [0,64Mi)     qT2 bf16 [b][n][512]
    //   [64,128Mi)   kbuf bf16
    //   [128,192Mi)  vbuf bf16
    //   [192,256Mi)  Xt bf16   -> after GEMM1: ctxp f32 (8Mi) @192,
    //                             rowm/rowr @200Mi, Wcb bf16 (8Mi) @201Mi
    //   [256Mi..)    Wqkvb(1.5Mi) Woutb(0.5Mi) rs1(256Ki)
    //   [259Mi..263Mi)  kpm/kps (2Mi each) — only if ws_size permits
    char* wsb = (char*)d_ws;
    ushort* qbuf  = (ushort*)wsb;
    ushort* kbuf  = (ushort*)(wsb + ((size_t)64 << 20));
    ushort* vbuf  = (ushort*)(wsb + ((size_t)128 << 20));
    ushort* Xt    = (ushort*)(wsb + ((size_t)192 << 20));
    float*  ctxp  = (float*)Xt;
    float*  rowm  = (float*)(wsb + ((size_t)200 << 20));
    float*  rowr  = rowm + 8192;
    ushort* Wcb   = (ushort*)(wsb + ((size_t)201 << 20));
    char*   tail  = wsb + ((size_t)256 << 20);
    ushort* Wqkvb = (ushort*)tail;
    ushort* Woutb = (ushort*)(tail + (size_t)1536 * 512 * 2);
    float*  rs1   = (float*)(tail + (size_t)1536 * 512 * 2 + (size_t)512 * 512 * 2);
    const bool fused_stats = ws_size >= ((size_t)263 << 20);
    float* kpm = fused_stats ? (float*)(wsb + ((size_t)259 << 20)) : nullptr;
    float* kps = fused_stats ? (float*)(wsb + ((size_t)261 << 20)) : nullptr;

    // 1. weight prep (merged)
    wprep2_k<<<1024, 256, 0, stream>>>(Wqkv, g1, Wout, Wqkvb, Woutb);
    // 2. Xt = bf16(x^T) + rs1 (full column sumsq in-kernel)
    transpose_k<<<dim3(64, 16), 256, 0, stream>>>(x, Xt, rs1);
    // 3. QKV GEMM (unified): qT2 (softmaxed), k (+LSE partials), v
    mfma_gemm<<<dim3(16, 6, B_), 512, 0, stream>>>(Wqkvb, Xt, rs1,
                                                   qbuf, kbuf, vbuf, kpm, kps);
    // 4. k row stats: LSE merge of GEMM1 partials (or fallback full pass)
    if (fused_stats)
        kstat_merge_k<<<32, 256, 0, stream>>>(kpm, kps, rowm, rowr);
    else
        rowstat_k<<<2048, 256, 0, stream>>>(kbuf, rowm, rowr);
    // 5. context partials (MFMA, softmax on the fly) -> ctxp[d][e]
    ctx_k<<<dim3(B_ * 8, 4), 256, 0, stream>>>(kbuf, vbuf, rowm, rowr, ctxp);
    // 6. Wc[b] = Wout @ ctx^T (per b,h)
    wcbuild_k<<<dim3(2, 8, B_), 256, 0, stream>>>(Woutb, ctxp, Wcb);
    // 7. output GEMM (per-b weights) + bias + rms-norm -> d_out f32 (final)
    gemm2_k<<<dim3(32, B_), 512, 0, stream>>>(Wcb, qbuf, bout, g2, out);
}

// Round 15
// 292.542 us; speedup vs baseline: 1.3223x; 1.3223x over previous
//
#include <hip/hip_runtime.h>
#include <hip/hip_bf16.h>
#include <math.h>

#define B_ 16
#define C_ 512
#define N_ 4096
#define NCOL (B_ * N_)  // 65536 columns (b, hw)

typedef short bf16x8 __attribute__((ext_vector_type(8)));
typedef ushort ushort8_t __attribute__((ext_vector_type(8)));
typedef float f32x4 __attribute__((ext_vector_type(4)));

__device__ __forceinline__ ushort f2bf(float f) {
    unsigned u = __float_as_uint(f);
    unsigned r = (u + 0x7FFFu + ((u >> 16) & 1u)) >> 16;
    return (ushort)r;
}
__device__ __forceinline__ float bf2f(ushort u) {
    return __uint_as_float((unsigned)u << 16);
}
__device__ __forceinline__ void gload_lds16(const void* g, void* l) {
    __builtin_amdgcn_global_load_lds(
        (const __attribute__((address_space(1))) unsigned int*)g,
        (__attribute__((address_space(3))) unsigned int*)l, 16, 0, 0);
}

// ---------------------------------------------------------------------------
// merged weight prep: Wqkvb[i] = bf16(Wqkv*g1), Woutb = bf16(Wout)
// ---------------------------------------------------------------------------
__global__ __launch_bounds__(256) void wprep2_k(const float* __restrict__ Wqkv,
                                                const float* __restrict__ g1,
                                                const float* __restrict__ Wout,
                                                ushort* __restrict__ Wqkvb,
                                                ushort* __restrict__ Woutb)
{
    int i = blockIdx.x * 256 + threadIdx.x;
    if (i < 196608) {                  // 1536*512/4 vectors
        float4 wv = reinterpret_cast<const float4*>(Wqkv)[i];
        const float4 gv = *reinterpret_cast<const float4*>(g1 + ((i * 4) & 511));
        ushort4 u;
        u.x = f2bf(wv.x * gv.x); u.y = f2bf(wv.y * gv.y);
        u.z = f2bf(wv.z * gv.z); u.w = f2bf(wv.w * gv.w);
        reinterpret_cast<ushort4*>(Wqkvb)[i] = u;
    } else {
        int j = i - 196608;            // < 65536
        float4 wv = reinterpret_cast<const float4*>(Wout)[j];
        ushort4 u;
        u.x = f2bf(wv.x); u.y = f2bf(wv.y); u.z = f2bf(wv.z); u.w = f2bf(wv.w);
        reinterpret_cast<ushort4*>(Woutb)[j] = u;
    }
}

// ---------------------------------------------------------------------------
// transpose v2: block = (64 n) x (all 512 c) x b.  float4 loads, LDS dbuf,
// Xt[b][n][c] = bf16(x[b][c][n]); rs1[b][n] computed in-kernel (full column).
// ---------------------------------------------------------------------------
__global__ __launch_bounds__(256) void transpose_k(const float* __restrict__ X,
                                                   ushort* __restrict__ Xt,
                                                   float* __restrict__ rs1)
{
    __shared__ float t[2][64][68];
    __shared__ float sr[16][64];
    const int b = blockIdx.y, n0 = blockIdx.x * 64;
    const int tid = threadIdx.x;
    const int tg = tid >> 4, tl = tid & 15;
    float sq[4] = {0.f, 0.f, 0.f, 0.f};
    for (int chunk = 0; chunk < 8; ++chunk) {
        const int buf = chunk & 1;
        const float* xp = X + ((size_t)b * C_ + chunk * 64) * N_ + n0;
        #pragma unroll
        for (int j = 0; j < 4; ++j) {
            int c = tg + j * 16;
            float4 v = *reinterpret_cast<const float4*>(xp + (size_t)c * N_ + tl * 4);
            *reinterpret_cast<float4*>(&t[buf][c][tl * 4]) = v;
            sq[0] += v.x * v.x; sq[1] += v.y * v.y;
            sq[2] += v.z * v.z; sq[3] += v.w * v.w;
        }
        __syncthreads();
        #pragma unroll
        for (int i = 0; i < 4; ++i) {
            int nl = tg + i * 16, cl = tl * 4;
            ushort4 u;
            u.x = f2bf(t[buf][cl + 0][nl]);
            u.y = f2bf(t[buf][cl + 1][nl]);
            u.z = f2bf(t[buf][cl + 2][nl]);
            u.w = f2bf(t[buf][cl + 3][nl]);
            *reinterpret_cast<ushort4*>(
                Xt + ((size_t)b * N_ + n0 + nl) * 512 + chunk * 64 + cl) = u;
        }
    }
    #pragma unroll
    for (int j = 0; j < 4; ++j) sr[tg][tl * 4 + j] = sq[j];
    __syncthreads();
    if (tid < 64) {
        float s = 0.f;
        #pragma unroll
        for (int g = 0; g < 16; ++g) s += sr[g][tid];
        rs1[(size_t)b * N_ + n0 + tid] = 22.627416998f / fmaxf(sqrtf(s), 1e-12f);
    }
}

// ---------------------------------------------------------------------------
// MFMA GEMM1 (256x256 tile, 8 waves 2x4, BK=64, double-buffered LDS,
// per-phase interleave + counted vmcnt):  acc[o][n] = sum_c A[o][c]*Bt[b][n][c]
// Epilogue (FROZEN — R10/R12/R14 variants all regressed): acc *= rs1[b][n];
//   part 0 (q): softmax over d * 0.125 -> qT2[b][n][h*64+d] bf16 (8B stores)
//   part 1/2 (k/v): -> bf16 raw [bh*64+d][n] (scalar stores)
// ---------------------------------------------------------------------------
__global__ __launch_bounds__(512, 2)
void mfma_gemm(const ushort* __restrict__ A, const ushort* __restrict__ Bt,
               const float* __restrict__ rs1,
               ushort* __restrict__ qT2, ushort* __restrict__ kd,
               ushort* __restrict__ vd)
{
    // lds[buf][A/B][256 rows][8 chunks][16B]
    __shared__ __align__(16) char lds[2][2][32768];
    const int b  = blockIdx.z;
    const int n0 = blockIdx.x * 256;
    const int m0 = blockIdx.y * 256;
    const int tid = threadIdx.x;
    const int w = tid >> 6, l = tid & 63;
    const int wm = w >> 2, wn = w & 3;          // 2 x 4 waves
    const int lq = l >> 4, lr = l & 15;
    const ushort* Bb = Bt + (size_t)b * N_ * 512;

    f32x4 acc[8][4];
    #pragma unroll
    for (int i = 0; i < 8; ++i)
        #pragma unroll
        for (int j = 0; j < 4; ++j)
            #pragma unroll
            for (int r = 0; r < 4; ++r) acc[i][j][r] = 0.f;

#define STAGE_STEP(t, i)                                                      \
    do {                                                                      \
        const int kb_ = (t) * 128;                                            \
        const int idx_ = (i) * 512 + tid;                                     \
        const int r_ = idx_ >> 3;                                             \
        const int ch_ = (idx_ & 7) ^ (r_ & 7);                                \
        gload_lds16((const char*)A + (size_t)(m0 + r_) * 1024 + kb_ + ch_ * 16,\
                    &lds[(t) & 1][0][idx_ * 16]);                             \
        gload_lds16((const char*)Bb + (size_t)(n0 + r_) * 1024 + kb_ + ch_ * 16,\
                    &lds[(t) & 1][1][idx_ * 16]);                             \
    } while (0)

    #pragma unroll
    for (int i = 0; i < 4; ++i) STAGE_STEP(0, i);

    bf16x8 bfr[4];
    #pragma unroll 2
    for (int t = 0; t < 8; ++t) {
        const char* As = lds[t & 1][0];
        const char* Bs = lds[t & 1][1];
        #pragma unroll
        for (int ph = 0; ph < 4; ++ph) {
            const int kk = ph >> 1, mg = ph & 1;
            bf16x8 af[4];
            if (ph != 0) {
                #pragma unroll
                for (int m2 = 0; m2 < 4; ++m2) {
                    int ra = wm * 128 + (mg * 4 + m2) * 16 + lr;
                    int ch = (kk * 4 + lq) ^ (ra & 7);
                    af[m2] = *(const bf16x8*)(As + ra * 128 + ch * 16);
                }
                if (mg == 0) {
                    #pragma unroll
                    for (int nf = 0; nf < 4; ++nf) {
                        int rb = wn * 64 + nf * 16 + lr;
                        int ch = (kk * 4 + lq) ^ (rb & 7);
                        bfr[nf] = *(const bf16x8*)(Bs + rb * 128 + ch * 16);
                    }
                }
            }
            if (t < 7) STAGE_STEP(t + 1, ph);
            if (ph == 0) {
                if (t < 7) { asm volatile("s_waitcnt vmcnt(2)" ::: "memory"); }
                else       { asm volatile("s_waitcnt vmcnt(0)" ::: "memory"); }
            }
            __builtin_amdgcn_s_barrier();
            if (ph == 0) {
                #pragma unroll
                for (int m2 = 0; m2 < 4; ++m2) {
                    int ra = wm * 128 + m2 * 16 + lr;
                    int ch = lq ^ (ra & 7);
                    af[m2] = *(const bf16x8*)(As + ra * 128 + ch * 16);
                }
                #pragma unroll
                for (int nf = 0; nf < 4; ++nf) {
                    int rb = wn * 64 + nf * 16 + lr;
                    int ch = lq ^ (rb & 7);
                    bfr[nf] = *(const bf16x8*)(Bs + rb * 128 + ch * 16);
                }
            }
            asm volatile("s_waitcnt lgkmcnt(0)" ::: "memory");
            __builtin_amdgcn_sched_barrier(0);
            __builtin_amdgcn_s_setprio(1);
            #pragma unroll
            for (int m2 = 0; m2 < 4; ++m2)
                #pragma unroll
                for (int nf = 0; nf < 4; ++nf)
                    acc[mg * 4 + m2][nf] = __builtin_amdgcn_mfma_f32_16x16x32_bf16(
                        af[m2], bfr[nf], acc[mg * 4 + m2][nf], 0, 0, 0);
            __builtin_amdgcn_s_setprio(0);
            __builtin_amdgcn_s_barrier();
        }
    }
#undef STAGE_STEP

    const int part = m0 >> 9;                       // block-uniform (0/1/2)
    const int mloc = (m0 & 511) + wm * 128;         // 0/128/256/384 within part
    const int nbase = n0 + wn * 64;
    if (part == 0) {
        // q: *rs1, softmax over the 64 d-rows of each head, *0.125,
        // write qT2[b][n][h*64+d] bf16 with packed 8B stores.
        #pragma unroll
        for (int hg = 0; hg < 2; ++hg) {
            const int head = (mloc >> 6) + hg;
            #pragma unroll
            for (int nf = 0; nf < 4; ++nf) {
                const int n = nbase + nf * 16 + lr;
                const float sc = rs1[(size_t)b * N_ + n];
                float v[4][4];
                float mx = -1e30f;
                #pragma unroll
                for (int m2 = 0; m2 < 4; ++m2)
                    #pragma unroll
                    for (int r = 0; r < 4; ++r) {
                        v[m2][r] = acc[hg * 4 + m2][nf][r] * sc;
                        mx = fmaxf(mx, v[m2][r]);
                    }
                mx = fmaxf(mx, __shfl_xor(mx, 16));
                mx = fmaxf(mx, __shfl_xor(mx, 32));
                float s = 0.f;
                #pragma unroll
                for (int m2 = 0; m2 < 4; ++m2)
                    #pragma unroll
                    for (int r = 0; r < 4; ++r) {
                        v[m2][r] = __expf(v[m2][r] - mx);
                        s += v[m2][r];
                    }
                s += __shfl_xor(s, 16);
                s += __shfl_xor(s, 32);
                const float r8 = 0.125f / s;
                ushort* qp = qT2 + ((size_t)b * N_ + n) * 512 + head * 64;
                #pragma unroll
                for (int m2 = 0; m2 < 4; ++m2) {
                    ushort4 u;
                    u.x = f2bf(v[m2][0] * r8);
                    u.y = f2bf(v[m2][1] * r8);
                    u.z = f2bf(v[m2][2] * r8);
                    u.w = f2bf(v[m2][3] * r8);
                    *reinterpret_cast<ushort4*>(qp + m2 * 16 + lq * 4) = u;
                }
            }
        }
    } else {
        ushort* dst = (part == 1) ? kd : vd;
        #pragma unroll
        for (int nf = 0; nf < 4; ++nf) {
            const int n = nbase + nf * 16 + lr;
            const float sc = rs1[(size_t)b * N_ + n];
            #pragma unroll
            for (int mf = 0; mf < 8; ++mf) {
                const int o = mloc + mf * 16 + lq * 4;
                #pragma unroll
                for (int r = 0; r < 4; ++r)
                    dst[((size_t)b * 512 + o + r) * N_ + n] =
                        f2bf(acc[mf][nf][r] * sc);
            }
        }
    }
}

// ---------------------------------------------------------------------------
// ctx (MFMA, max-free softmax): ctxp[bh][chunk][d][e] =
//     sum_{n in chunk} exp(k[bh][d][n]) * v[bh][e][n]     (UNNORMALIZED)
// srowp[bh][chunk][d] = sum_{n in chunk} exp(k[bh][d][n])  (denominator part)
// k values are O(1) (rms-normed input x 1/sqrt(512) weights) -> exp safe.
// ---------------------------------------------------------------------------
__global__ __launch_bounds__(256) void ctx_k(const ushort* __restrict__ kk,
                                             const ushort* __restrict__ vv,
                                             float* __restrict__ ctxp,
                                             float* __restrict__ srowp)
{
    const int bh = blockIdx.x, chunk = blockIdx.y;
    const ushort* kp = kk + (size_t)bh * 64 * N_;
    const ushort* vp = vv + (size_t)bh * 64 * N_;
    __shared__ __align__(16) ushort kx[64 * 128];   // 16 KiB
    __shared__ __align__(16) ushort vx[64 * 128];   // 16 KiB
    const int tid = threadIdx.x;
    const int w = tid >> 6, l = tid & 63;
    const int lq = l >> 4, lr = l & 15;
    const int we = w >> 1, wd = w & 1;              // e-half, d-half of 64x64

    f32x4 acc[2][2];
    #pragma unroll
    for (int i = 0; i < 2; ++i)
        #pragma unroll
        for (int j = 0; j < 2; ++j)
            #pragma unroll
            for (int r = 0; r < 4; ++r) acc[i][j][r] = 0.f;

    float se[4] = {0.f, 0.f, 0.f, 0.f};   // per-i row partial exp-sums

    for (int s = 0; s < 8; ++s) {
        const int n0 = chunk * 1024 + s * 128;
        #pragma unroll
        for (int i = 0; i < 4; ++i) {
            int idx = i * 256 + tid;
            int row = idx >> 4;
            int ch  = (idx & 15) ^ (row & 15);
            gload_lds16((const char*)(vp + (size_t)row * N_ + n0 + ch * 8),
                        (char*)vx + idx * 16);
        }
        #pragma unroll
        for (int i = 0; i < 4; ++i) {
            int idx = i * 256 + tid;
            int row = idx >> 4;
            int ch  = idx & 15;
            ushort8_t u = *reinterpret_cast<const ushort8_t*>(
                kp + (size_t)row * N_ + n0 + ch * 8);
            ushort8_t o;
            float ss = 0.f;
            #pragma unroll
            for (int t = 0; t < 8; ++t) {
                float e = __expf(bf2f(u[t]));
                ss += e;
                o[t] = f2bf(e);
            }
            se[i] += ss;
            *(ushort8_t*)((char*)kx + (row * 16 + (ch ^ (row & 15))) * 16) = o;
        }
        __syncthreads();
        #pragma unroll
        for (int k2 = 0; k2 < 4; ++k2) {
            bf16x8 af[2], bfr[2];
            #pragma unroll
            for (int i = 0; i < 2; ++i) {
                int re = we * 32 + i * 16 + lr;
                int cha = (k2 * 4 + lq) ^ (re & 15);
                af[i] = *(const bf16x8*)((const char*)vx + (re * 16 + cha) * 16);
                int rd = wd * 32 + i * 16 + lr;
                int chb = (k2 * 4 + lq) ^ (rd & 15);
                bfr[i] = *(const bf16x8*)((const char*)kx + (rd * 16 + chb) * 16);
            }
            #pragma unroll
            for (int i = 0; i < 2; ++i)
                #pragma unroll
                for (int j = 0; j < 2; ++j)
                    acc[i][j] = __builtin_amdgcn_mfma_f32_16x16x32_bf16(
                        af[i], bfr[j], acc[i][j], 0, 0, 0);
        }
        __syncthreads();
    }

    // denominator partials: reduce se[i] across the 16 lr-lanes of each row
    #pragma unroll
    for (int i = 0; i < 4; ++i) {
        float v = se[i];
        v += __shfl_xor(v, 1);
        v += __shfl_xor(v, 2);
        v += __shfl_xor(v, 4);
        v += __shfl_xor(v, 8);
        if (lr == 0) {
            const int row = i * 16 + w * 4 + lq;
            srowp[((size_t)bh * 4 + chunk) * 64 + row] = v;
        }
    }

    // write ctxp[bh][chunk][d][e] (e contiguous -> float4), UNNORMALIZED
    float* cbase = ctxp + ((size_t)bh * 4 + chunk) * 4096;
    #pragma unroll
    for (int j = 0; j < 2; ++j) {
        const int d = wd * 32 + j * 16 + lr;
        #pragma unroll
        for (int i = 0; i < 2; ++i) {
            const int e0 = we * 32 + i * 16 + lq * 4;
            float4 wv;
            wv.x = acc[i][j][0];
            wv.y = acc[i][j][1];
            wv.z = acc[i][j][2];
            wv.w = acc[i][j][3];
            *reinterpret_cast<float4*>(cbase + (size_t)d * 64 + e0) = wv;
        }
    }
}

// ---------------------------------------------------------------------------
// wcbuild (MFMA): Wc[b][o][h*64+d] = bf16( sum_e Wout[o][h*64+e] *
//     (sum_chunk ctxp[bh][chunk][d][e]) / (sum_chunk srowp[bh][chunk][d]) )
// ---------------------------------------------------------------------------
__global__ __launch_bounds__(256) void wcbuild_k(const ushort* __restrict__ Wb,
                                                 const float* __restrict__ ctxp,
                                                 const float* __restrict__ srowp,
                                                 ushort* __restrict__ Wc)
{
    const int oh = blockIdx.x, h = blockIdx.y, b = blockIdx.z;
    const int bh = b * 8 + h;
    __shared__ __align__(16) ushort ws[256 * 64];   // 32 KiB, Wout slice
    __shared__ __align__(16) ushort cs[64 * 64];    // 8 KiB, ctx[d][e]
    const int tid = threadIdx.x;
    const int w = tid >> 6, l = tid & 63;
    const int lq = l >> 4, lr = l & 15;

    #pragma unroll
    for (int i = 0; i < 8; ++i) {
        int idx = i * 256 + tid;
        int row = idx >> 3;
        int ch = (idx & 7) ^ (row & 7);
        gload_lds16(Wb + (size_t)(oh * 256 + row) * 512 + h * 64 + ch * 8,
                    (char*)ws + idx * 16);
    }
    {
        const float* cp = ctxp + (size_t)bh * 4 * 4096;
        const float* sp = srowp + (size_t)bh * 4 * 64;
        const int d = tid >> 2, eb = (tid & 3) * 16;
        const float rinv = 1.f / (sp[d] + sp[64 + d] + sp[128 + d] + sp[192 + d]);
        float vs[16];
        #pragma unroll
        for (int t4 = 0; t4 < 4; ++t4) {
            float4 a0 = *(const float4*)(cp + d * 64 + eb + t4 * 4);
            float4 a1 = *(const float4*)(cp + 4096 + d * 64 + eb + t4 * 4);
            float4 a2 = *(const float4*)(cp + 8192 + d * 64 + eb + t4 * 4);
            float4 a3 = *(const float4*)(cp + 12288 + d * 64 + eb + t4 * 4);
            vs[t4 * 4 + 0] = (a0.x + a1.x + a2.x + a3.x) * rinv;
            vs[t4 * 4 + 1] = (a0.y + a1.y + a2.y + a3.y) * rinv;
            vs[t4 * 4 + 2] = (a0.z + a1.z + a2.z + a3.z) * rinv;
            vs[t4 * 4 + 3] = (a0.w + a1.w + a2.w + a3.w) * rinv;
        }
        ushort8_t o0, o1;
        #pragma unroll
        for (int t = 0; t < 8; ++t) { o0[t] = f2bf(vs[t]); o1[t] = f2bf(vs[8 + t]); }
        const int c0 = (eb >> 3) ^ (d & 7);
        const int c1 = ((eb >> 3) + 1) ^ (d & 7);
        *(ushort8_t*)((char*)cs + (d * 8 + c0) * 16) = o0;
        *(ushort8_t*)((char*)cs + (d * 8 + c1) * 16) = o1;
    }
    __syncthreads();

    f32x4 acc[4][4];
    #pragma unroll
    for (int i = 0; i < 4; ++i)
        #pragma unroll
        for (int j = 0; j < 4; ++j)
            #pragma unroll
            for (int r = 0; r < 4; ++r) acc[i][j][r] = 0.f;

    #pragma unroll
    for (int kk = 0; kk < 2; ++kk) {
        bf16x8 af[4], bfr[4];
        #pragma unroll
        for (int mf = 0; mf < 4; ++mf) {
            int ra = w * 64 + mf * 16 + lr;
            int ch = (kk * 4 + lq) ^ (ra & 7);
            af[mf] = *(const bf16x8*)((const char*)ws + (ra * 8 + ch) * 16);
        }
        #pragma unroll
        for (int nf = 0; nf < 4; ++nf) {
            int rd = nf * 16 + lr;
            int ch = (kk * 4 + lq) ^ (rd & 7);
            bfr[nf] = *(const bf16x8*)((const char*)cs + (rd * 8 + ch) * 16);
        }
        #pragma unroll
        for (int mf = 0; mf < 4; ++mf)
            #pragma unroll
            for (int nf = 0; nf < 4; ++nf)
                acc[mf][nf] = __builtin_amdgcn_mfma_f32_16x16x32_bf16(
                    af[mf], bfr[nf], acc[mf][nf], 0, 0, 0);
    }

    ushort* wp = Wc + (size_t)b * 262144 + h * 64;
    #pragma unroll
    for (int mf = 0; mf < 4; ++mf)
        #pragma unroll
        for (int r = 0; r < 4; ++r) {
            const int o = oh * 256 + w * 64 + mf * 16 + lq * 4 + r;
            #pragma unroll
            for (int nf = 0; nf < 4; ++nf)
                wp[(size_t)o * 512 + nf * 16 + lr] = f2bf(acc[mf][nf][r]);
        }
}

// ---------------------------------------------------------------------------
// GEMM2 fused: out[b][o][n] = rmsnorm(Wc[b]@qT2[b] + bias) * g2, full column
// per block. 512 threads = 8 waves; wave w owns rows [w*64,w*64+64), n-tile 128.
// ---------------------------------------------------------------------------
__global__ __launch_bounds__(512, 2)
void gemm2_k(const ushort* __restrict__ Wc,     // [b][512][512] bf16
             const ushort* __restrict__ Bt,     // qT2 [b][n][512] bf16
             const float* __restrict__ bias,
             const float* __restrict__ g2,
             float* __restrict__ outp)
{
    __shared__ __align__(16) ushort As[512 * 64];   // 64 KiB
    __shared__ __align__(16) ushort Bs[128 * 64];   // 16 KiB
    const int b  = blockIdx.y;
    const int n0 = blockIdx.x * 128;
    const int tid = threadIdx.x;
    const int w = tid >> 6, l = tid & 63;
    const int lq = l >> 4, lr = l & 15;
    const ushort* A  = Wc + (size_t)b * 262144;
    const ushort* Bb = Bt + (size_t)b * N_ * 512;

    f32x4 acc[4][8];
    #pragma unroll
    for (int i = 0; i < 4; ++i)
        #pragma unroll
        for (int j = 0; j < 8; ++j)
            #pragma unroll
            for (int r = 0; r < 4; ++r) acc[i][j][r] = 0.f;

    for (int k0 = 0; k0 < 512; k0 += 64) {
        #pragma unroll
        for (int i = 0; i < 8; ++i) {
            int base = i * 512 + w * 64;
            int idx = base + l;
            int r = idx >> 3, ch = (idx & 7) ^ (r & 7);
            gload_lds16((const char*)A + (size_t)r * 1024 + k0 * 2 + ch * 16,
                        (char*)As + (size_t)base * 16);
        }
        #pragma unroll
        for (int i = 0; i < 2; ++i) {
            int base = i * 512 + w * 64;
            int idx = base + l;
            int r = idx >> 3, ch = (idx & 7) ^ (r & 7);
            gload_lds16((const char*)Bb + (size_t)(n0 + r) * 1024 + k0 * 2 + ch * 16,
                        (char*)Bs + (size_t)base * 16);
        }
        __syncthreads();
        #pragma unroll
        for (int kk = 0; kk < 2; ++kk) {
            bf16x8 af[4], bfv[8];
            #pragma unroll
            for (int mf = 0; mf < 4; ++mf) {
                int ra = w * 64 + mf * 16 + lr;
                int ch = (kk * 4 + lq) ^ (ra & 7);
                af[mf] = *(const bf16x8*)((const char*)As + ra * 128 + ch * 16);
            }
            #pragma unroll
            for (int nf = 0; nf < 8; ++nf) {
                int rb = nf * 16 + lr;
                int ch = (kk * 4 + lq) ^ (rb & 7);
                bfv[nf] = *(const bf16x8*)((const char*)Bs + rb * 128 + ch * 16);
            }
            #pragma unroll
            for (int mf = 0; mf < 4; ++mf)
                #pragma unroll
                for (int nf = 0; nf < 8; ++nf)
                    acc[mf][nf] = __builtin_amdgcn_mfma_f32_16x16x32_bf16(
                        af[mf], bfv[nf], acc[mf][nf], 0, 0, 0);
        }
        __syncthreads();
    }

    float4 bv[4], g2v[4];
    #pragma unroll
    for (int mf = 0; mf < 4; ++mf) {
        bv[mf]  = *reinterpret_cast<const float4*>(bias + w * 64 + mf * 16 + lq * 4);
        g2v[mf] = *reinterpret_cast<const float4*>(g2   + w * 64 + mf * 16 + lq * 4);
    }
    float csq[8] = {};
    #pragma unroll
    for (int mf = 0; mf < 4; ++mf)
        #pragma unroll
        for (int nf = 0; nf < 8; ++nf)
            #pragma unroll
            for (int r = 0; r < 4; ++r) {
                float wv = acc[mf][nf][r] + ((const float*)&bv[mf])[r];
                acc[mf][nf][r] = wv;
                csq[nf] += wv * wv;
            }
    #pragma unroll
    for (int nf = 0; nf < 8; ++nf) {
        csq[nf] += __shfl_xor(csq[nf], 16);
        csq[nf] += __shfl_xor(csq[nf], 32);
    }
    float* red  = (float*)As;
    float* rs2s = red + 1024;
    if (lq == 0) {
        #pragma unroll
        for (int nf = 0; nf < 8; ++nf)
            red[w * 128 + nf * 16 + lr] = csq[nf];
    }
    __syncthreads();
    if (tid < 128) {
        float s = 0.f;
        #pragma unroll
        for (int j = 0; j < 8; ++j) s += red[j * 128 + tid];
        rs2s[tid] = 22.627416998f / fmaxf(sqrtf(s), 1e-12f);
    }
    __syncthreads();
    #pragma unroll
    for (int nf = 0; nf < 8; ++nf) {
        const float rsv = rs2s[nf * 16 + lr];
        const int n = n0 + nf * 16 + lr;
        #pragma unroll
        for (int mf = 0; mf < 4; ++mf) {
            const int o = w * 64 + mf * 16 + lq * 4;
            float* p = outp + ((size_t)b * 512 + o) * N_ + n;
            #pragma unroll
            for (int r = 0; r < 4; ++r)
                p[(size_t)r * N_] = acc[mf][nf][r] * rsv * ((const float*)&g2v[mf])[r];
        }
    }
}

// ---------------------------------------------------------------------------
extern "C" void kernel_launch(void* const* d_in, const int* in_sizes, int n_in,
                              void* d_out, int out_size, void* d_ws, size_t ws_size,
                              hipStream_t stream)
{
    const float* x    = (const float*)d_in[0];
    const float* g1   = (const float*)d_in[1];
    const float* Wqkv = (const float*)d_in[2];
    const float* Wout = (const float*)d_in[3];
    const float* bout = (const float*)d_in[4];
    const float* g2   = (const float*)d_in[5];
    float* out = (float*)d_out;

    // ws layout (<= 258.25 MiB):
    //   [0,64Mi)     qT2 bf16 [b][n][512]
    //   [64,128Mi)   kbuf bf16
    //   [128,192Mi)  vbuf bf16
    //   [192,256Mi)  Xt bf16   -> after GEMM1: ctxp f32 (8Mi) @192,
    //                             srowp (128Ki) @200Mi, Wcb bf16 (8Mi) @201Mi
    //   [256Mi..)    Wqkvb(1.5Mi) Woutb(0.5Mi) rs1(256Ki)
    char* wsb = (char*)d_ws;
    ushort* qbuf  = (ushort*)wsb;
    ushort* kbuf  = (ushort*)(wsb + ((size_t)64 << 20));
    ushort* vbuf  = (ushort*)(wsb + ((size_t)128 << 20));
    ushort* Xt    = (ushort*)(wsb + ((size_t)192 << 20));
    float*  ctxp  = (float*)Xt;
    float*  srowp = (float*)(wsb + ((size_t)200 << 20));
    ushort* Wcb   = (ushort*)(wsb + ((size_t)201 << 20));
    char*   tail  = wsb + ((size_t)256 << 20);
    ushort* Wqkvb = (ushort*)tail;
    ushort* Woutb = (ushort*)(tail + (size_t)1536 * 512 * 2);
    float*  rs1   = (float*)(tail + (size_t)1536 * 512 * 2 + (size_t)512 * 512 * 2);

    // 1. weight prep (merged)
    wprep2_k<<<1024, 256, 0, stream>>>(Wqkv, g1, Wout, Wqkvb, Woutb);
    // 2. Xt = bf16(x^T) + rs1 (full column sumsq in-kernel)
    transpose_k<<<dim3(64, 16), 256, 0, stream>>>(x, Xt, rs1);
    // 3. QKV GEMM (unified): qT2 (softmaxed, [b][n][hd]), k, v (bf16)
    mfma_gemm<<<dim3(16, 6, B_), 512, 0, stream>>>(Wqkvb, Xt, rs1,
                                                   qbuf, kbuf, vbuf);
    // 4. context partials + per-row exp-sum partials (max-free softmax)
    ctx_k<<<dim3(B_ * 8, 4), 256, 0, stream>>>(kbuf, vbuf, ctxp, srowp);
    // 5. Wc[b] = Wout @ (ctx/denominator)^T  (per b,h)
    wcbuild_k<<<dim3(2, 8, B_), 256, 0, stream>>>(Woutb, ctxp, srowp, Wcb);
    // 6. output GEMM (per-b weights) + bias + rms-norm -> d_out f32 (final)
    gemm2_k<<<dim3(32, B_), 512, 0, stream>>>(Wcb, qbuf, bout, g2, out);
}